// Round 1
// baseline (1551.354 us; speedup 1.0000x reference)
//
#include <hip/hip_runtime.h>
#include <math.h>

#define N_NODES 50000
#define N_EDGES 1600000
#define N_GRAPHS 512
#define F_IN 9
#define H 64

// conv1 edge phase: m = relu(x[src] + a*e1w + e1b); atomic scatter to aggr1[dst]
__global__ void edge1_kernel(const float* __restrict__ x,
                             const int* __restrict__ ei,
                             const float* __restrict__ ea,
                             const float* __restrict__ e1w,
                             const float* __restrict__ e1b,
                             float* __restrict__ aggr1) {
    int e = blockIdx.x * blockDim.x + threadIdx.x;
    if (e >= N_EDGES) return;
    int s = ei[e];
    int d = ei[N_EDGES + e];
    float a = ea[e];
#pragma unroll
    for (int f = 0; f < F_IN; ++f) {
        float m = fmaxf(x[s * F_IN + f] + a * e1w[f] + e1b[f], 0.f);
        atomicAdd(&aggr1[d * F_IN + f], m);
    }
}

// conv1 node MLP: h1 = relu(relu((x+aggr1) @ w1a^T + b1a) @ w1b^T + b1b)
// one wave per node, lane = output feature
__global__ void node1_kernel(const float* __restrict__ x,
                             const float* __restrict__ aggr1,
                             const float* __restrict__ w1a,
                             const float* __restrict__ b1a,
                             const float* __restrict__ w1b,
                             const float* __restrict__ b1b,
                             float* __restrict__ h1) {
    int n = blockIdx.x * (blockDim.x >> 6) + (threadIdx.x >> 6);
    int f = threadIdx.x & 63;
    if (n >= N_NODES) return;
    float acc = b1a[f];
#pragma unroll
    for (int k = 0; k < F_IN; ++k)
        acc += (x[n * F_IN + k] + aggr1[n * F_IN + k]) * w1a[f * F_IN + k];
    float ha = fmaxf(acc, 0.f);
    float acc2 = b1b[f];
#pragma unroll
    for (int k = 0; k < H; ++k)
        acc2 += __shfl(ha, k, 64) * w1b[f * H + k];
    h1[n * H + f] = fmaxf(acc2, 0.f);
}

// conv2 edge phase: thread = (edge, feat). Wave handles one edge:
// coalesced gather of h1[src*64..+63], coalesced atomics to aggr2[dst*64..]
__global__ void edge2_kernel(const float* __restrict__ h1,
                             const int* __restrict__ ei,
                             const float* __restrict__ ea,
                             const float* __restrict__ e2w,
                             const float* __restrict__ e2b,
                             float* __restrict__ aggr2) {
    int t = blockIdx.x * blockDim.x + threadIdx.x;
    int e = t >> 6;
    if (e >= N_EDGES) return;
    int f = t & 63;
    int s = ei[e];
    int d = ei[N_EDGES + e];
    float m = fmaxf(h1[s * H + f] + ea[e] * e2w[f] + e2b[f], 0.f);
    atomicAdd(&aggr2[d * H + f], m);
}

// conv2 node MLP + readout + per-graph expense accumulation
__global__ void node2_kernel(const float* __restrict__ h1,
                             const float* __restrict__ aggr2,
                             const float* __restrict__ w2a,
                             const float* __restrict__ b2a,
                             const float* __restrict__ w2b,
                             const float* __restrict__ b2b,
                             const float* __restrict__ wr1,
                             const float* __restrict__ br1,
                             const float* __restrict__ wr2,
                             const float* __restrict__ br2,
                             const int* __restrict__ term,
                             const float* __restrict__ ccost,
                             const int* __restrict__ batch,
                             float* __restrict__ pi,
                             float* __restrict__ te) {
    int n = blockIdx.x * (blockDim.x >> 6) + (threadIdx.x >> 6);
    int f = threadIdx.x & 63;
    if (n >= N_NODES) return;
    float h = h1[n * H + f] + aggr2[n * H + f];
    float acc = b2a[f];
#pragma unroll
    for (int k = 0; k < H; ++k)
        acc += __shfl(h, k, 64) * w2a[f * H + k];
    float h2a = fmaxf(acc, 0.f);
    float acc2 = b2b[f];
#pragma unroll
    for (int k = 0; k < H; ++k)
        acc2 += __shfl(h2a, k, 64) * w2b[f * H + k];
    float h2 = fmaxf(acc2, 0.f);
    // readout layer 1 (32 outputs); lanes 32..63 duplicate 0..31 to stay convergent
    int fr = f & 31;
    float accr = br1[fr];
#pragma unroll
    for (int k = 0; k < H; ++k)
        accr += __shfl(h2, k, 64) * wr1[fr * H + k];
    float r = fmaxf(accr, 0.f);
    // readout layer 2: dot over 32, count each lane once
    float val = (f < 32) ? r * wr2[fr] : 0.f;
#pragma unroll
    for (int off = 32; off > 0; off >>= 1)
        val += __shfl_xor(val, off, 64);
    if (f == 0) {
        float z = val + br2[0];
        float sig = 1.f / (1.f + expf(-z));
        float p = sig * (1.f - (float)term[n]);
        pi[n] = p;
        atomicAdd(&te[batch[n]], p * ccost[n]);
    }
}

__global__ void final_kernel(const float* __restrict__ pi,
                             const int* __restrict__ batch,
                             const float* __restrict__ Btot,
                             const float* __restrict__ te,
                             float* __restrict__ out) {
    int n = blockIdx.x * blockDim.x + threadIdx.x;
    if (n >= N_NODES) return;
    int b = batch[n];
    float ratio = fminf(Btot[b] / (te[b] + 1e-12f), 1.f);
    out[n] = pi[n] * ratio;
}

extern "C" void kernel_launch(void* const* d_in, const int* in_sizes, int n_in,
                              void* d_out, int out_size, void* d_ws, size_t ws_size,
                              hipStream_t stream) {
    const float* x     = (const float*)d_in[0];
    const int*   ei    = (const int*)d_in[1];
    const float* ea    = (const float*)d_in[2];
    const int*   batch = (const int*)d_in[3];
    const float* Btot  = (const float*)d_in[4];
    const int*   term  = (const int*)d_in[5];
    const float* ccost = (const float*)d_in[6];
    const float* e1w   = (const float*)d_in[7];
    const float* e1b   = (const float*)d_in[8];
    const float* w1a   = (const float*)d_in[9];
    const float* b1a   = (const float*)d_in[10];
    const float* w1b   = (const float*)d_in[11];
    const float* b1b   = (const float*)d_in[12];
    const float* e2w   = (const float*)d_in[13];
    const float* e2b   = (const float*)d_in[14];
    const float* w2a   = (const float*)d_in[15];
    const float* b2a   = (const float*)d_in[16];
    const float* w2b   = (const float*)d_in[17];
    const float* b2b   = (const float*)d_in[18];
    const float* wr1   = (const float*)d_in[19];
    const float* br1   = (const float*)d_in[20];
    const float* wr2   = (const float*)d_in[21];
    const float* br2   = (const float*)d_in[22];

    float* ws    = (float*)d_ws;
    float* aggr1 = ws;                          // N*9
    float* aggr2 = aggr1 + N_NODES * F_IN;      // N*64
    float* te    = aggr2 + (size_t)N_NODES * H; // G
    float* h1    = te + N_GRAPHS;               // N*64
    float* pi    = h1 + (size_t)N_NODES * H;    // N
    float* out   = (float*)d_out;

    size_t zero_elems = (size_t)N_NODES * F_IN + (size_t)N_NODES * H + N_GRAPHS;
    hipMemsetAsync(ws, 0, zero_elems * sizeof(float), stream);

    edge1_kernel<<<(N_EDGES + 255) / 256, 256, 0, stream>>>(x, ei, ea, e1w, e1b, aggr1);
    node1_kernel<<<(N_NODES + 3) / 4, 256, 0, stream>>>(x, aggr1, w1a, b1a, w1b, b1b, h1);
    edge2_kernel<<<(N_EDGES / 4) /* E*64/256 = 400000 */, 256, 0, stream>>>(h1, ei, ea, e2w, e2b, aggr2);
    node2_kernel<<<(N_NODES + 3) / 4, 256, 0, stream>>>(h1, aggr2, w2a, b2a, w2b, b2b,
                                                        wr1, br1, wr2, br2,
                                                        term, ccost, batch, pi, te);
    final_kernel<<<(N_NODES + 255) / 256, 256, 0, stream>>>(pi, batch, Btot, te, out);
}

// Round 2
// 879.506 us; speedup vs baseline: 1.7639x; 1.7639x over previous
//
#include <hip/hip_runtime.h>
#include <math.h>

#define N_NODES 50000
#define N_EDGES 1600000
#define N_GRAPHS 512
#define F_IN 9
#define H 64

// ---------- CSR build ----------
__global__ void hist_kernel(const int* __restrict__ ei, int* __restrict__ deg) {
    int e = blockIdx.x * blockDim.x + threadIdx.x;
    if (e >= N_EDGES) return;
    atomicAdd(&deg[ei[N_EDGES + e]], 1);
}

// single-block exclusive scan over deg[N_NODES] -> starts, next (copy)
__global__ void scan_kernel(const int* __restrict__ deg,
                            int* __restrict__ starts,
                            int* __restrict__ next) {
    __shared__ int wsum[16];
    __shared__ int woff[16];
    int tid = threadIdx.x, lane = tid & 63, wid = tid >> 6;
    int run = 0;
    for (int base = 0; base < N_NODES; base += 1024) {
        int i = base + tid;
        int v = (i < N_NODES) ? deg[i] : 0;
        int incl = v;
#pragma unroll
        for (int off = 1; off < 64; off <<= 1) {
            int t = __shfl_up(incl, off, 64);
            if (lane >= off) incl += t;
        }
        if (lane == 63) wsum[wid] = incl;
        __syncthreads();
        if (wid == 0) {
            int wv = (lane < 16) ? wsum[lane] : 0;
            int winc = wv;
#pragma unroll
            for (int off = 1; off < 16; off <<= 1) {
                int t = __shfl_up(winc, off, 64);
                if (lane >= off) winc += t;
            }
            if (lane < 16) woff[lane] = winc - wv;  // exclusive
        }
        __syncthreads();
        int excl = run + woff[wid] + (incl - v);
        if (i < N_NODES) { starts[i] = excl; next[i] = excl; }
        run += woff[15] + wsum[15];
        __syncthreads();  // protect wsum/woff before next chunk overwrites
    }
}

__global__ void scatter_kernel(const int* __restrict__ ei,
                               const float* __restrict__ ea,
                               int* __restrict__ next,
                               int* __restrict__ esrc,
                               float* __restrict__ eat) {
    int e = blockIdx.x * blockDim.x + threadIdx.x;
    if (e >= N_EDGES) return;
    int d = ei[N_EDGES + e];
    int pos = atomicAdd(&next[d], 1);
    esrc[pos] = ei[e];
    eat[pos] = ea[e];
}

// ---------- conv1 aggregation (no atomics): 16 lanes per dst, f<9 active ----------
__global__ void agg1_kernel(const float* __restrict__ x,
                            const int* __restrict__ starts,
                            const int* __restrict__ deg,
                            const int* __restrict__ esrc,
                            const float* __restrict__ eat,
                            const float* __restrict__ e1w,
                            const float* __restrict__ e1b,
                            float* __restrict__ aggr1) {
    int t = blockIdx.x * blockDim.x + threadIdx.x;
    int g = t >> 4;
    int f = t & 15;
    if (g >= N_NODES) return;
    int s0 = starts[g], dg = deg[g];
    float wf = (f < F_IN) ? e1w[f] : 0.f;
    float bf = (f < F_IN) ? e1b[f] : 0.f;
    float acc = 0.f;
    for (int j = 0; j < dg; ++j) {
        int s = esrc[s0 + j];
        float a = eat[s0 + j];
        if (f < F_IN)
            acc += fmaxf(x[s * F_IN + f] + a * wf + bf, 0.f);
    }
    if (f < F_IN) aggr1[g * F_IN + f] = acc;
}

// ---------- conv1 node MLP: wave per node, lane = output feature ----------
__global__ void node1_kernel(const float* __restrict__ x,
                             const float* __restrict__ aggr1,
                             const float* __restrict__ w1a,
                             const float* __restrict__ b1a,
                             const float* __restrict__ w1b,
                             const float* __restrict__ b1b,
                             float* __restrict__ h1) {
    int n = blockIdx.x * (blockDim.x >> 6) + (threadIdx.x >> 6);
    int f = threadIdx.x & 63;
    if (n >= N_NODES) return;
    float acc = b1a[f];
#pragma unroll
    for (int k = 0; k < F_IN; ++k)
        acc += (x[n * F_IN + k] + aggr1[n * F_IN + k]) * w1a[f * F_IN + k];
    float ha = fmaxf(acc, 0.f);
    float acc2 = b1b[f];
#pragma unroll
    for (int k = 0; k < H; ++k)
        acc2 += __shfl(ha, k, 64) * w1b[f * H + k];
    h1[n * H + f] = fmaxf(acc2, 0.f);
}

// ---------- conv2 aggregation + node MLP + readout, fused: wave per node ----------
__global__ void agg2_node2_kernel(const float* __restrict__ h1,
                                  const int* __restrict__ starts,
                                  const int* __restrict__ deg,
                                  const int* __restrict__ esrc,
                                  const float* __restrict__ eat,
                                  const float* __restrict__ e2w,
                                  const float* __restrict__ e2b,
                                  const float* __restrict__ w2a,
                                  const float* __restrict__ b2a,
                                  const float* __restrict__ w2b,
                                  const float* __restrict__ b2b,
                                  const float* __restrict__ wr1,
                                  const float* __restrict__ br1,
                                  const float* __restrict__ wr2,
                                  const float* __restrict__ br2,
                                  const int* __restrict__ term,
                                  const float* __restrict__ ccost,
                                  const int* __restrict__ batch,
                                  float* __restrict__ pi,
                                  float* __restrict__ te) {
    int n = blockIdx.x * (blockDim.x >> 6) + (threadIdx.x >> 6);
    int f = threadIdx.x & 63;
    if (n >= N_NODES) return;
    int s0 = starts[n], dg = deg[n];
    float wf = e2w[f], bf = e2b[f];
    float acc = 0.f;
    for (int j = 0; j < dg; ++j) {
        int s = esrc[s0 + j];   // wave-uniform address -> broadcast from L1
        float a = eat[s0 + j];
        acc += fmaxf(h1[s * H + f] + a * wf + bf, 0.f);  // 256 B coalesced gather
    }
    float h = h1[n * H + f] + acc;
    float a1 = b2a[f];
#pragma unroll
    for (int k = 0; k < H; ++k)
        a1 += __shfl(h, k, 64) * w2a[f * H + k];
    float h2a = fmaxf(a1, 0.f);
    float a2 = b2b[f];
#pragma unroll
    for (int k = 0; k < H; ++k)
        a2 += __shfl(h2a, k, 64) * w2b[f * H + k];
    float h2 = fmaxf(a2, 0.f);
    // readout layer 1 (32 outs); lanes 32..63 duplicate 0..31
    int fr = f & 31;
    float accr = br1[fr];
#pragma unroll
    for (int k = 0; k < H; ++k)
        accr += __shfl(h2, k, 64) * wr1[fr * H + k];
    float r = fmaxf(accr, 0.f);
    float val = (f < 32) ? r * wr2[fr] : 0.f;
#pragma unroll
    for (int off = 32; off > 0; off >>= 1)
        val += __shfl_xor(val, off, 64);
    if (f == 0) {
        float z = val + br2[0];
        float sig = 1.f / (1.f + expf(-z));
        float p = sig * (1.f - (float)term[n]);
        pi[n] = p;
        atomicAdd(&te[batch[n]], p * ccost[n]);
    }
}

__global__ void final_kernel(const float* __restrict__ pi,
                             const int* __restrict__ batch,
                             const float* __restrict__ Btot,
                             const float* __restrict__ te,
                             float* __restrict__ out) {
    int n = blockIdx.x * blockDim.x + threadIdx.x;
    if (n >= N_NODES) return;
    int b = batch[n];
    float ratio = fminf(Btot[b] / (te[b] + 1e-12f), 1.f);
    out[n] = pi[n] * ratio;
}

extern "C" void kernel_launch(void* const* d_in, const int* in_sizes, int n_in,
                              void* d_out, int out_size, void* d_ws, size_t ws_size,
                              hipStream_t stream) {
    const float* x     = (const float*)d_in[0];
    const int*   ei    = (const int*)d_in[1];
    const float* ea    = (const float*)d_in[2];
    const int*   batch = (const int*)d_in[3];
    const float* Btot  = (const float*)d_in[4];
    const int*   term  = (const int*)d_in[5];
    const float* ccost = (const float*)d_in[6];
    const float* e1w   = (const float*)d_in[7];
    const float* e1b   = (const float*)d_in[8];
    const float* w1a   = (const float*)d_in[9];
    const float* b1a   = (const float*)d_in[10];
    const float* w1b   = (const float*)d_in[11];
    const float* b1b   = (const float*)d_in[12];
    const float* e2w   = (const float*)d_in[13];
    const float* e2b   = (const float*)d_in[14];
    const float* w2a   = (const float*)d_in[15];
    const float* b2a   = (const float*)d_in[16];
    const float* w2b   = (const float*)d_in[17];
    const float* b2b   = (const float*)d_in[18];
    const float* wr1   = (const float*)d_in[19];
    const float* br1   = (const float*)d_in[20];
    const float* wr2   = (const float*)d_in[21];
    const float* br2   = (const float*)d_in[22];

    // workspace layout (4-byte elements)
    char* p = (char*)d_ws;
    int*   deg    = (int*)p;                    p += sizeof(int)   * N_NODES;   // zeroed
    float* te     = (float*)p;                  p += sizeof(float) * N_GRAPHS;  // zeroed
    int*   starts = (int*)p;                    p += sizeof(int)   * N_NODES;
    int*   next   = (int*)p;                    p += sizeof(int)   * N_NODES;
    int*   esrc   = (int*)p;                    p += sizeof(int)   * N_EDGES;
    float* eat    = (float*)p;                  p += sizeof(float) * N_EDGES;
    float* aggr1  = (float*)p;                  p += sizeof(float) * N_NODES * F_IN;
    float* h1     = (float*)p;                  p += sizeof(float) * (size_t)N_NODES * H;
    float* pi     = (float*)p;                  p += sizeof(float) * N_NODES;
    float* out    = (float*)d_out;

    hipMemsetAsync(d_ws, 0, sizeof(int) * N_NODES + sizeof(float) * N_GRAPHS, stream);

    hist_kernel<<<(N_EDGES + 255) / 256, 256, 0, stream>>>(ei, deg);
    scan_kernel<<<1, 1024, 0, stream>>>(deg, starts, next);
    scatter_kernel<<<(N_EDGES + 255) / 256, 256, 0, stream>>>(ei, ea, next, esrc, eat);
    agg1_kernel<<<(N_NODES * 16 + 255) / 256, 256, 0, stream>>>(x, starts, deg, esrc, eat,
                                                                e1w, e1b, aggr1);
    node1_kernel<<<(N_NODES + 3) / 4, 256, 0, stream>>>(x, aggr1, w1a, b1a, w1b, b1b, h1);
    agg2_node2_kernel<<<(N_NODES + 3) / 4, 256, 0, stream>>>(h1, starts, deg, esrc, eat,
                                                             e2w, e2b, w2a, b2a, w2b, b2b,
                                                             wr1, br1, wr2, br2,
                                                             term, ccost, batch, pi, te);
    final_kernel<<<(N_NODES + 255) / 256, 256, 0, stream>>>(pi, batch, Btot, te, out);
}

// Round 3
// 756.455 us; speedup vs baseline: 2.0508x; 1.1627x over previous
//
#include <hip/hip_runtime.h>
#include <math.h>

#define N_NODES 50000
#define N_EDGES 1600000
#define N_GRAPHS 512
#define F_IN 9
#define H 64

// ---------- CSR build ----------
__global__ void hist_kernel(const int* __restrict__ ei, int* __restrict__ deg) {
    int e = blockIdx.x * blockDim.x + threadIdx.x;
    if (e >= N_EDGES) return;
    atomicAdd(&deg[ei[N_EDGES + e]], 1);
}

// single-block exclusive scan over deg[N_NODES] -> starts, next (copy)
__global__ void scan_kernel(const int* __restrict__ deg,
                            int* __restrict__ starts,
                            int* __restrict__ next) {
    __shared__ int wsum[16];
    __shared__ int woff[16];
    int tid = threadIdx.x, lane = tid & 63, wid = tid >> 6;
    int run = 0;
    for (int base = 0; base < N_NODES; base += 1024) {
        int i = base + tid;
        int v = (i < N_NODES) ? deg[i] : 0;
        int incl = v;
#pragma unroll
        for (int off = 1; off < 64; off <<= 1) {
            int t = __shfl_up(incl, off, 64);
            if (lane >= off) incl += t;
        }
        if (lane == 63) wsum[wid] = incl;
        __syncthreads();
        if (wid == 0) {
            int wv = (lane < 16) ? wsum[lane] : 0;
            int winc = wv;
#pragma unroll
            for (int off = 1; off < 16; off <<= 1) {
                int t = __shfl_up(winc, off, 64);
                if (lane >= off) winc += t;
            }
            if (lane < 16) woff[lane] = winc - wv;  // exclusive
        }
        __syncthreads();
        int excl = run + woff[wid] + (incl - v);
        if (i < N_NODES) { starts[i] = excl; next[i] = excl; }
        run += woff[15] + wsum[15];
        __syncthreads();
    }
}

// pack (src, attr) into one int2 -> one 8B scattered store per edge
__global__ void scatter_kernel(const int* __restrict__ ei,
                               const float* __restrict__ ea,
                               int* __restrict__ next,
                               int2* __restrict__ epay) {
    int e = blockIdx.x * blockDim.x + threadIdx.x;
    if (e >= N_EDGES) return;
    int d = ei[N_EDGES + e];
    int pos = atomicAdd(&next[d], 1);
    epay[pos] = make_int2(ei[e], __float_as_int(ea[e]));
}

// ---------- conv1 fused: aggregation (4 edge-slots x 16 feat-lanes) + MLP ----------
__global__ void conv1_kernel(const float* __restrict__ x,
                             const int* __restrict__ starts,
                             const int* __restrict__ deg,
                             const int2* __restrict__ epay,
                             const float* __restrict__ e1w,
                             const float* __restrict__ e1b,
                             const float* __restrict__ w1a,
                             const float* __restrict__ b1a,
                             const float* __restrict__ w1b,
                             const float* __restrict__ b1b,
                             float* __restrict__ h1) {
    int n = blockIdx.x * (blockDim.x >> 6) + (threadIdx.x >> 6);
    int lane = threadIdx.x & 63;
    if (n >= N_NODES) return;
    int slot = lane >> 4;    // 0..3 : which edge within a group of 4
    int f = lane & 15;       // 0..15, f < 9 active
    int s0 = starts[n], dg = deg[n];
    bool act = f < F_IN;
    float wf = act ? e1w[f] : 0.f;
    float bf = act ? e1b[f] : 0.f;
    float acc = 0.f;
    for (int j = slot; j < dg; j += 4) {
        int2 p = epay[s0 + j];              // 16 lanes broadcast same 8B
        float xv = act ? x[p.x * F_IN + f] : 0.f;
        float m = xv + __int_as_float(p.y) * wf + bf;
        acc += act ? fmaxf(m, 0.f) : 0.f;
    }
    // reduce the 4 slots: after these, every lane holds agg[f] for f = lane&15
    acc += __shfl_xor(acc, 16, 64);
    acc += __shfl_xor(acc, 32, 64);
    // lanes 0..8 pick up (x[n,f] + agg[f]); others contribute 0
    float xa = (lane < F_IN) ? x[n * F_IN + lane] + acc : 0.f;
    // layer A: lane = output feature (64)
    float a1 = b1a[lane];
#pragma unroll
    for (int k = 0; k < F_IN; ++k)
        a1 += __shfl(xa, k, 64) * w1a[lane * F_IN + k];
    float ha = fmaxf(a1, 0.f);
    // layer B
    float a2 = b1b[lane];
#pragma unroll
    for (int k = 0; k < H; ++k)
        a2 += __shfl(ha, k, 64) * w1b[lane * H + k];
    h1[n * H + lane] = fmaxf(a2, 0.f);
}

// ---------- conv2 aggregation (unroll 8 for MLP) + node MLP + readout ----------
__global__ void agg2_node2_kernel(const float* __restrict__ h1,
                                  const int* __restrict__ starts,
                                  const int* __restrict__ deg,
                                  const int2* __restrict__ epay,
                                  const float* __restrict__ e2w,
                                  const float* __restrict__ e2b,
                                  const float* __restrict__ w2a,
                                  const float* __restrict__ b2a,
                                  const float* __restrict__ w2b,
                                  const float* __restrict__ b2b,
                                  const float* __restrict__ wr1,
                                  const float* __restrict__ br1,
                                  const float* __restrict__ wr2,
                                  const float* __restrict__ br2,
                                  const int* __restrict__ term,
                                  const float* __restrict__ ccost,
                                  const int* __restrict__ batch,
                                  float* __restrict__ pi,
                                  float* __restrict__ te) {
    int n = blockIdx.x * (blockDim.x >> 6) + (threadIdx.x >> 6);
    int f = threadIdx.x & 63;
    if (n >= N_NODES) return;
    int s0 = starts[n], dg = deg[n];
    const int2* ep = epay + s0;
    float wf = e2w[f], bf = e2b[f];
    float acc = 0.f;
    int j = 0;
    // 8 independent gathers in flight per iteration
    for (; j + 8 <= dg; j += 8) {
        int2 p0 = ep[j    ], p1 = ep[j + 1], p2 = ep[j + 2], p3 = ep[j + 3];
        int2 p4 = ep[j + 4], p5 = ep[j + 5], p6 = ep[j + 6], p7 = ep[j + 7];
        float v0 = h1[p0.x * H + f], v1 = h1[p1.x * H + f];
        float v2 = h1[p2.x * H + f], v3 = h1[p3.x * H + f];
        float v4 = h1[p4.x * H + f], v5 = h1[p5.x * H + f];
        float v6 = h1[p6.x * H + f], v7 = h1[p7.x * H + f];
        acc += fmaxf(v0 + __int_as_float(p0.y) * wf + bf, 0.f)
             + fmaxf(v1 + __int_as_float(p1.y) * wf + bf, 0.f)
             + fmaxf(v2 + __int_as_float(p2.y) * wf + bf, 0.f)
             + fmaxf(v3 + __int_as_float(p3.y) * wf + bf, 0.f)
             + fmaxf(v4 + __int_as_float(p4.y) * wf + bf, 0.f)
             + fmaxf(v5 + __int_as_float(p5.y) * wf + bf, 0.f)
             + fmaxf(v6 + __int_as_float(p6.y) * wf + bf, 0.f)
             + fmaxf(v7 + __int_as_float(p7.y) * wf + bf, 0.f);
    }
    for (; j < dg; ++j) {
        int2 p = ep[j];
        acc += fmaxf(h1[p.x * H + f] + __int_as_float(p.y) * wf + bf, 0.f);
    }
    float h = h1[n * H + f] + acc;
    float a1 = b2a[f];
#pragma unroll
    for (int k = 0; k < H; ++k)
        a1 += __shfl(h, k, 64) * w2a[f * H + k];
    float h2a = fmaxf(a1, 0.f);
    float a2 = b2b[f];
#pragma unroll
    for (int k = 0; k < H; ++k)
        a2 += __shfl(h2a, k, 64) * w2b[f * H + k];
    float h2 = fmaxf(a2, 0.f);
    int fr = f & 31;
    float accr = br1[fr];
#pragma unroll
    for (int k = 0; k < H; ++k)
        accr += __shfl(h2, k, 64) * wr1[fr * H + k];
    float r = fmaxf(accr, 0.f);
    float val = (f < 32) ? r * wr2[fr] : 0.f;
#pragma unroll
    for (int off = 32; off > 0; off >>= 1)
        val += __shfl_xor(val, off, 64);
    if (f == 0) {
        float z = val + br2[0];
        float sig = 1.f / (1.f + expf(-z));
        float p = sig * (1.f - (float)term[n]);
        pi[n] = p;
        atomicAdd(&te[batch[n]], p * ccost[n]);
    }
}

__global__ void final_kernel(const float* __restrict__ pi,
                             const int* __restrict__ batch,
                             const float* __restrict__ Btot,
                             const float* __restrict__ te,
                             float* __restrict__ out) {
    int n = blockIdx.x * blockDim.x + threadIdx.x;
    if (n >= N_NODES) return;
    int b = batch[n];
    float ratio = fminf(Btot[b] / (te[b] + 1e-12f), 1.f);
    out[n] = pi[n] * ratio;
}

extern "C" void kernel_launch(void* const* d_in, const int* in_sizes, int n_in,
                              void* d_out, int out_size, void* d_ws, size_t ws_size,
                              hipStream_t stream) {
    const float* x     = (const float*)d_in[0];
    const int*   ei    = (const int*)d_in[1];
    const float* ea    = (const float*)d_in[2];
    const int*   batch = (const int*)d_in[3];
    const float* Btot  = (const float*)d_in[4];
    const int*   term  = (const int*)d_in[5];
    const float* ccost = (const float*)d_in[6];
    const float* e1w   = (const float*)d_in[7];
    const float* e1b   = (const float*)d_in[8];
    const float* w1a   = (const float*)d_in[9];
    const float* b1a   = (const float*)d_in[10];
    const float* w1b   = (const float*)d_in[11];
    const float* b1b   = (const float*)d_in[12];
    const float* e2w   = (const float*)d_in[13];
    const float* e2b   = (const float*)d_in[14];
    const float* w2a   = (const float*)d_in[15];
    const float* b2a   = (const float*)d_in[16];
    const float* w2b   = (const float*)d_in[17];
    const float* b2b   = (const float*)d_in[18];
    const float* wr1   = (const float*)d_in[19];
    const float* br1   = (const float*)d_in[20];
    const float* wr2   = (const float*)d_in[21];
    const float* br2   = (const float*)d_in[22];

    char* p = (char*)d_ws;
    int*   deg    = (int*)p;    p += sizeof(int)   * N_NODES;   // zeroed
    float* te     = (float*)p;  p += sizeof(float) * N_GRAPHS;  // zeroed
    int*   starts = (int*)p;    p += sizeof(int)   * N_NODES;
    int*   next   = (int*)p;    p += sizeof(int)   * N_NODES;
    int2*  epay   = (int2*)p;   p += sizeof(int2)  * (size_t)N_EDGES;
    float* h1     = (float*)p;  p += sizeof(float) * (size_t)N_NODES * H;
    float* pi     = (float*)p;  p += sizeof(float) * N_NODES;
    float* out    = (float*)d_out;

    hipMemsetAsync(d_ws, 0, sizeof(int) * N_NODES + sizeof(float) * N_GRAPHS, stream);

    hist_kernel<<<(N_EDGES + 255) / 256, 256, 0, stream>>>(ei, deg);
    scan_kernel<<<1, 1024, 0, stream>>>(deg, starts, next);
    scatter_kernel<<<(N_EDGES + 255) / 256, 256, 0, stream>>>(ei, ea, next, epay);
    conv1_kernel<<<(N_NODES + 3) / 4, 256, 0, stream>>>(x, starts, deg, epay,
                                                        e1w, e1b, w1a, b1a, w1b, b1b, h1);
    agg2_node2_kernel<<<(N_NODES + 3) / 4, 256, 0, stream>>>(h1, starts, deg, epay,
                                                             e2w, e2b, w2a, b2a, w2b, b2b,
                                                             wr1, br1, wr2, br2,
                                                             term, ccost, batch, pi, te);
    final_kernel<<<(N_NODES + 255) / 256, 256, 0, stream>>>(pi, batch, Btot, te, out);
}